// Round 14
// baseline (981.926 us; speedup 1.0000x reference)
//
#include <hip/hip_runtime.h>
#include <hip/hip_cooperative_groups.h>

namespace cg = cooperative_groups;

typedef unsigned short ushort_t;
typedef unsigned int uint_t;

#define BKT_SHIFT 7            // 128 dst-nodes per bucket
#define BKT_NODES 128
#define NBKT_MAX 800           // >= ceil(100000/128)=782
#define SCOL_CAP 4096          // fine_fill LDS col staging (16 KB); mean bucket = 3200
#define NPB 32                 // nodes per agg chunk
#define SCOL_N 1536            // agg LDS col cache (mean 800, +26 sigma)
#define EPB_C 8192             // classic path: edges per block (512 thr x 16)
#define MAXGRID 2048

__device__ __forceinline__ ushort_t f2bf(float f) {
    unsigned u = __float_as_uint(f);
    unsigned r = (u + 0x7FFFu + ((u >> 16) & 1u)) >> 16;   // RNE
    return (ushort_t)r;
}
__device__ __forceinline__ float bflo(uint_t u) { return __uint_as_float(u << 16); }
__device__ __forceinline__ float bfhi(uint_t u) { return __uint_as_float(u & 0xFFFF0000u); }

// ======================= shared agg inner loop ===========================
// 32 nodes x 8 lanes; uint2 loads (8 edges per gather wave-inst).

struct AggSm {
    float sWa[512], sWb[512], sba[16], sbb[32];
    float sv[NPB * 33], st1[NPB * 17];
    int scol[SCOL_N];
};

template <bool RELU_OUT, bool OUT_BF16>
__device__ __forceinline__ void agg_chunk(AggSm& A, const uint2* __restrict__ x2,
                                          const int* __restrict__ rp,
                                          const int* __restrict__ col,
                                          void* outv, int N, int base) {
    int t = threadIdx.x;
    int kb = rp[base];
    int kt = rp[min(base + NPB, N)];
    int tot = kt - kb;
    bool ovf = (tot > SCOL_N);
    if (!ovf) {
        for (int i = t; i < tot; i += 256)
            A.scol[i] = __builtin_nontemporal_load(col + kb + i);
    }
    __syncthreads();                       // B1: scol ready

    int ln = t >> 3, sl = t & 7;
    int n = base + ln;
    bool act = (n < N);
    if (act) {
        uint2 us = x2[(size_t)n * 8 + sl];
        float v0 = bflo(us.x), v1 = bfhi(us.x), v2 = bflo(us.y), v3 = bfhi(us.y);
        int ks = rp[n], ke = rp[n + 1];
        if (!ovf) {
            int k = ks - kb, kend = ke - kb;
            for (; k + 8 <= kend; k += 8) {
                int s0 = A.scol[k + 0], s1 = A.scol[k + 1];
                int s2 = A.scol[k + 2], s3 = A.scol[k + 3];
                int s4 = A.scol[k + 4], s5 = A.scol[k + 5];
                int s6 = A.scol[k + 6], s7 = A.scol[k + 7];
                uint2 u0 = x2[(size_t)s0 * 8 + sl];
                uint2 u1 = x2[(size_t)s1 * 8 + sl];
                uint2 u2 = x2[(size_t)s2 * 8 + sl];
                uint2 u3 = x2[(size_t)s3 * 8 + sl];
                uint2 u4 = x2[(size_t)s4 * 8 + sl];
                uint2 u5 = x2[(size_t)s5 * 8 + sl];
                uint2 u6 = x2[(size_t)s6 * 8 + sl];
                uint2 u7 = x2[(size_t)s7 * 8 + sl];
                v0 += ((bflo(u0.x) + bflo(u1.x)) + (bflo(u2.x) + bflo(u3.x)))
                    + ((bflo(u4.x) + bflo(u5.x)) + (bflo(u6.x) + bflo(u7.x)));
                v1 += ((bfhi(u0.x) + bfhi(u1.x)) + (bfhi(u2.x) + bfhi(u3.x)))
                    + ((bfhi(u4.x) + bfhi(u5.x)) + (bfhi(u6.x) + bfhi(u7.x)));
                v2 += ((bflo(u0.y) + bflo(u1.y)) + (bflo(u2.y) + bflo(u3.y)))
                    + ((bflo(u4.y) + bflo(u5.y)) + (bflo(u6.y) + bflo(u7.y)));
                v3 += ((bfhi(u0.y) + bfhi(u1.y)) + (bfhi(u2.y) + bfhi(u3.y)))
                    + ((bfhi(u4.y) + bfhi(u5.y)) + (bfhi(u6.y) + bfhi(u7.y)));
            }
            for (; k < kend; ++k) {
                uint2 u = x2[(size_t)A.scol[k] * 8 + sl];
                v0 += bflo(u.x); v1 += bfhi(u.x); v2 += bflo(u.y); v3 += bfhi(u.y);
            }
        } else {
            for (int k = ks; k < ke; ++k) {
                uint2 u = x2[(size_t)col[k] * 8 + sl];
                v0 += bflo(u.x); v1 += bfhi(u.x); v2 += bflo(u.y); v3 += bfhi(u.y);
            }
        }
        int c0 = sl * 4;
        A.sv[ln * 33 + c0 + 0] = v0; A.sv[ln * 33 + c0 + 1] = v1;
        A.sv[ln * 33 + c0 + 2] = v2; A.sv[ln * 33 + c0 + 3] = v3;
    }
    __syncthreads();                       // B2: sv ready

    if (act) {
        float ha = A.sba[sl], hb = A.sba[sl + 8];
        #pragma unroll
        for (int cc = 0; cc < 32; ++cc) {
            float vc = A.sv[ln * 33 + cc];
            ha += vc * A.sWa[cc * 16 + sl];
            hb += vc * A.sWa[cc * 16 + sl + 8];
        }
        A.st1[ln * 17 + sl]     = fmaxf(ha, 0.f);
        A.st1[ln * 17 + sl + 8] = fmaxf(hb, 0.f);
    }
    __syncthreads();                       // B3: st1 ready

    if (act) {
        int c0 = sl * 4;
        float a0 = A.sbb[c0], a1 = A.sbb[c0 + 1];
        float a2 = A.sbb[c0 + 2], a3 = A.sbb[c0 + 3];
        #pragma unroll
        for (int j = 0; j < 16; ++j) {
            float hj = A.st1[ln * 17 + j];
            a0 += hj * A.sWb[j * 32 + c0];
            a1 += hj * A.sWb[j * 32 + c0 + 1];
            a2 += hj * A.sWb[j * 32 + c0 + 2];
            a3 += hj * A.sWb[j * 32 + c0 + 3];
        }
        if (RELU_OUT) {
            a0 = fmaxf(a0, 0.f); a1 = fmaxf(a1, 0.f);
            a2 = fmaxf(a2, 0.f); a3 = fmaxf(a3, 0.f);
        }
        if (OUT_BF16) {
            uint_t p0 = (uint_t)f2bf(a0) | ((uint_t)f2bf(a1) << 16);
            uint_t p1 = (uint_t)f2bf(a2) | ((uint_t)f2bf(a3) << 16);
            uint_t* o = (uint_t*)outv + (size_t)n * 16 + sl * 2;
            __builtin_nontemporal_store(p0, o);
            __builtin_nontemporal_store(p1, o + 1);
        } else {
            float* o = (float*)outv + (size_t)n * 32 + c0;
            __builtin_nontemporal_store(a0, o);
            __builtin_nontemporal_store(a1, o + 1);
            __builtin_nontemporal_store(a2, o + 2);
            __builtin_nontemporal_store(a3, o + 3);
        }
    }
    __syncthreads();                       // B4: safe to overwrite scol next chunk
}

template <bool RELU_OUT, bool OUT_BF16>
__device__ void agg_phase(AggSm& A, const ushort_t* xin,
                          const int* __restrict__ rp, const int* __restrict__ col,
                          const float* Wa, const float* ba,
                          const float* Wb, const float* bb,
                          void* outv, int N, int nchunks) {
    int t = threadIdx.x;
    A.sWa[t] = Wa[t];  A.sWa[t + 256] = Wa[t + 256];
    A.sWb[t] = Wb[t];  A.sWb[t + 256] = Wb[t + 256];
    if (t < 16) A.sba[t] = ba[t];
    if (t < 32) A.sbb[t] = bb[t];
    const uint2* x2 = (const uint2*)xin;
    for (int c = blockIdx.x; c < nchunks; c += gridDim.x)
        agg_chunk<RELU_OUT, OUT_BF16>(A, x2, rp, col, outv, N, c * NPB);
}

// ======================= cooperative mega kernel =========================

union SMem {
    int lcnt[NBKT_MAX];
    int lds[256];
    struct { int lbase[NBKT_MAX]; int lcur[NBKT_MAX]; } scat;
    struct { int scnt[256]; int srel[256]; int scur[256]; int scol[SCOL_CAP]; } ff;
    AggSm agg;
};

struct MegaP {
    const float4* x;
    const int* src; const int* dst;
    const float* W1; const float* b1; const float* W2; const float* b2;
    const float* W3; const float* b3; const float* W4; const float* b4;
    float* out;
    int* hist; int* T; int* Tscan; int* staged; int* rp; int* col;
    ushort_t* xb; ushort_t* hb;
    int N, E, NBKT, n4, EPB2, nchunks;
};

__global__ void __launch_bounds__(256, 6) mega(MegaP p) {
    cg::grid_group grid = cg::this_grid();
    __shared__ SMem sm;
    int t = threadIdx.x, blk = blockIdx.x;

    // P0: x -> bf16
    for (int i = blk * 256 + t; i < p.n4; i += gridDim.x * 256) {
        float4 v = p.x[i];
        p.xb[i * 4 + 0] = f2bf(v.x);
        p.xb[i * 4 + 1] = f2bf(v.y);
        p.xb[i * 4 + 2] = f2bf(v.z);
        p.xb[i * 4 + 3] = f2bf(v.w);
    }

    // P1: per-block bucket histogram
    for (int b = t; b < p.NBKT; b += 256) sm.lcnt[b] = 0;
    __syncthreads();
    int e0 = blk * p.EPB2;
    int e1 = min(e0 + p.EPB2, p.E);
    for (int e = e0 + t; e < e1; e += 256)
        atomicAdd(&sm.lcnt[p.dst[e] >> BKT_SHIFT], 1);
    __syncthreads();
    for (int b = t; b < p.NBKT; b += 256) p.hist[blk * p.NBKT + b] = sm.lcnt[b];
    grid.sync();

    // P2a: column scan over gridDim.x rows (generic)
    if (blk < p.NBKT) {
        int b = blk;
        int NB = gridDim.x;
        int R = (NB + 255) >> 8;
        int r0 = t * R, r1 = min(r0 + R, NB);
        int sum = 0;
        for (int r = r0; r < r1; ++r) sum += p.hist[r * p.NBKT + b];
        sm.lds[t] = sum;
        __syncthreads();
        for (int off = 1; off < 256; off <<= 1) {
            int add = (t >= off) ? sm.lds[t - off] : 0;
            __syncthreads();
            sm.lds[t] += add;
            __syncthreads();
        }
        int pp = (t == 0) ? 0 : sm.lds[t - 1];
        for (int r = r0; r < r1; ++r) {
            int v = p.hist[r * p.NBKT + b];
            p.hist[r * p.NBKT + b] = pp;
            pp += v;
        }
        if (t == 255) p.T[b] = sm.lds[255];
    }
    grid.sync();

    // P2b: scan bucket totals (block 0)
    if (blk == 0) {
        int base = t * 4;
        int v0 = (base + 0 < p.NBKT) ? p.T[base + 0] : 0;
        int v1 = (base + 1 < p.NBKT) ? p.T[base + 1] : 0;
        int v2 = (base + 2 < p.NBKT) ? p.T[base + 2] : 0;
        int v3 = (base + 3 < p.NBKT) ? p.T[base + 3] : 0;
        sm.lds[t] = v0 + v1 + v2 + v3;
        __syncthreads();
        for (int off = 1; off < 256; off <<= 1) {
            int add = (t >= off) ? sm.lds[t - off] : 0;
            __syncthreads();
            sm.lds[t] += add;
            __syncthreads();
        }
        int pp = (t == 0) ? 0 : sm.lds[t - 1];
        if (base + 0 < p.NBKT) p.Tscan[base + 0] = pp;  pp += v0;
        if (base + 1 < p.NBKT) p.Tscan[base + 1] = pp;  pp += v1;
        if (base + 2 < p.NBKT) p.Tscan[base + 2] = pp;  pp += v2;
        if (base + 3 < p.NBKT) p.Tscan[base + 3] = pp;
        if (t == 0) p.Tscan[p.NBKT] = p.E;
    }
    grid.sync();

    // P3: ranked scatter
    for (int b = t; b < p.NBKT; b += 256) {
        sm.scat.lbase[b] = p.hist[blk * p.NBKT + b] + p.Tscan[b];
        sm.scat.lcur[b] = 0;
    }
    __syncthreads();
    for (int e = e0 + t; e < e1; e += 256) {
        int d = p.dst[e], s = p.src[e];
        int b = d >> BKT_SHIFT;
        int r = atomicAdd(&sm.scat.lcur[b], 1);
        p.staged[sm.scat.lbase[b] + r] = ((d & (BKT_NODES - 1)) << 24) | s;
    }
    grid.sync();

    // P4: fine fill
    if (blk < p.NBKT) {
        int b = blk;
        int n0 = b << BKT_SHIFT;
        int nn = min(BKT_NODES, p.N - n0);
        int fe0 = p.Tscan[b], fe1 = p.Tscan[b + 1];
        int m = fe1 - fe0;
        sm.ff.scnt[t] = 0; sm.ff.scur[t] = 0;
        __syncthreads();
        for (int i = t; i < m; i += 256)
            atomicAdd(&sm.ff.scnt[((unsigned)p.staged[fe0 + i]) >> 24], 1);
        __syncthreads();
        int inc = sm.ff.scnt[t];
        for (int off = 1; off < 256; off <<= 1) {
            int add = (t >= off) ? sm.ff.scnt[t - off] : 0;
            __syncthreads();
            sm.ff.scnt[t] += add;
            __syncthreads();
        }
        int excl = sm.ff.scnt[t] - inc;
        sm.ff.srel[t] = excl;
        if (t < nn) p.rp[n0 + t] = fe0 + excl;
        if (b == p.NBKT - 1 && t == 0) p.rp[p.N] = p.E;
        __syncthreads();
        if (m <= SCOL_CAP) {
            for (int i = t; i < m; i += 256) {
                int v = p.staged[fe0 + i];
                int dl = ((unsigned)v) >> 24;
                int pos = sm.ff.srel[dl] + atomicAdd(&sm.ff.scur[dl], 1);
                sm.ff.scol[pos] = v & 0xFFFFFF;
            }
            __syncthreads();
            for (int i = t; i < m; i += 256) p.col[fe0 + i] = sm.ff.scol[i];
        } else {
            for (int i = t; i < m; i += 256) {
                int v = p.staged[fe0 + i];
                int dl = ((unsigned)v) >> 24;
                int pos = sm.ff.srel[dl] + atomicAdd(&sm.ff.scur[dl], 1);
                p.col[fe0 + pos] = v & 0xFFFFFF;
            }
        }
    }
    grid.sync();

    // P5/P6: the two convs
    agg_phase<true, true>(sm.agg, p.xb, p.rp, p.col,
                          p.W1, p.b1, p.W2, p.b2, p.hb, p.N, p.nchunks);
    grid.sync();
    agg_phase<false, false>(sm.agg, p.hb, p.rp, p.col,
                            p.W3, p.b3, p.W4, p.b4, p.out, p.N, p.nchunks);
}

// ======================= classic fallback kernels ========================

__global__ void to_bf16_c(const float4* __restrict__ in, ushort_t* __restrict__ out,
                          int n4) {
    int i = blockIdx.x * blockDim.x + threadIdx.x;
    if (i < n4) {
        float4 v = in[i];
        out[i * 4 + 0] = f2bf(v.x);
        out[i * 4 + 1] = f2bf(v.y);
        out[i * 4 + 2] = f2bf(v.z);
        out[i * 4 + 3] = f2bf(v.w);
    }
}

__global__ void histA_c(const int* __restrict__ dst, int* __restrict__ hist,
                        int E, int NBKT) {
    __shared__ int lcnt[NBKT_MAX];
    int t = threadIdx.x, blk = blockIdx.x;
    for (int b = t; b < NBKT; b += 512) lcnt[b] = 0;
    __syncthreads();
    int e0 = blk * EPB_C;
    #pragma unroll
    for (int i = 0; i < 16; ++i) {
        int e = e0 + i * 512 + t;
        if (e < E) atomicAdd(&lcnt[dst[e] >> BKT_SHIFT], 1);
    }
    __syncthreads();
    for (int b = t; b < NBKT; b += 512) hist[blk * NBKT + b] = lcnt[b];
}

__global__ void colscan_c(int* __restrict__ hist, int* __restrict__ T,
                          int NBLK, int NBKT) {
    __shared__ int lds[256];
    int b = blockIdx.x, t = threadIdx.x;
    int j0 = t * 4;
    int v0 = (j0 + 0 < NBLK) ? hist[(j0 + 0) * NBKT + b] : 0;
    int v1 = (j0 + 1 < NBLK) ? hist[(j0 + 1) * NBKT + b] : 0;
    int v2 = (j0 + 2 < NBLK) ? hist[(j0 + 2) * NBKT + b] : 0;
    int v3 = (j0 + 3 < NBLK) ? hist[(j0 + 3) * NBKT + b] : 0;
    lds[t] = v0 + v1 + v2 + v3;
    __syncthreads();
    for (int off = 1; off < 256; off <<= 1) {
        int add = (t >= off) ? lds[t - off] : 0;
        __syncthreads();
        lds[t] += add;
        __syncthreads();
    }
    int p = (t == 0) ? 0 : lds[t - 1];
    if (j0 + 0 < NBLK) hist[(j0 + 0) * NBKT + b] = p;  p += v0;
    if (j0 + 1 < NBLK) hist[(j0 + 1) * NBKT + b] = p;  p += v1;
    if (j0 + 2 < NBLK) hist[(j0 + 2) * NBKT + b] = p;  p += v2;
    if (j0 + 3 < NBLK) hist[(j0 + 3) * NBKT + b] = p;
    if (t == 255) T[b] = lds[255];
}

__global__ void scan_small_c(const int* __restrict__ in, int* __restrict__ out,
                             int M, int E) {
    __shared__ int lds[1024];
    int t = threadIdx.x;
    int base = t * 4;
    int v0 = (base + 0 < M) ? in[base + 0] : 0;
    int v1 = (base + 1 < M) ? in[base + 1] : 0;
    int v2 = (base + 2 < M) ? in[base + 2] : 0;
    int v3 = (base + 3 < M) ? in[base + 3] : 0;
    lds[t] = v0 + v1 + v2 + v3;
    __syncthreads();
    for (int off = 1; off < 1024; off <<= 1) {
        int add = (t >= off) ? lds[t - off] : 0;
        __syncthreads();
        lds[t] += add;
        __syncthreads();
    }
    int p = (t == 0) ? 0 : lds[t - 1];
    if (base + 0 < M) out[base + 0] = p;  p += v0;
    if (base + 1 < M) out[base + 1] = p;  p += v1;
    if (base + 2 < M) out[base + 2] = p;  p += v2;
    if (base + 3 < M) out[base + 3] = p;
    if (t == 0) out[M] = E;
}

__global__ void scatter_c(const int* __restrict__ src, const int* __restrict__ dst,
                          const int* __restrict__ hist, const int* __restrict__ Tscan,
                          int* __restrict__ staged, int E, int NBKT) {
    __shared__ int lbase[NBKT_MAX];
    __shared__ int lcur[NBKT_MAX];
    int t = threadIdx.x, blk = blockIdx.x;
    for (int b = t; b < NBKT; b += 512) {
        lbase[b] = hist[blk * NBKT + b] + Tscan[b];
        lcur[b] = 0;
    }
    __syncthreads();
    int e0 = blk * EPB_C;
    #pragma unroll
    for (int i = 0; i < 16; ++i) {
        int e = e0 + i * 512 + t;
        if (e < E) {
            int d = dst[e], s = src[e];
            int b = d >> BKT_SHIFT;
            int r = atomicAdd(&lcur[b], 1);
            staged[lbase[b] + r] = ((d & (BKT_NODES - 1)) << 24) | s;
        }
    }
}

__global__ void fine_fill_c(const int* __restrict__ staged, const int* __restrict__ Tscan,
                            int* __restrict__ rp, int* __restrict__ col,
                            int N, int E, int NBKT) {
    __shared__ int scnt[256];
    __shared__ int srel[256];
    __shared__ int scur[256];
    __shared__ int scol[SCOL_CAP];
    int b = blockIdx.x, t = threadIdx.x;
    int n0 = b << BKT_SHIFT;
    int nn = min(BKT_NODES, N - n0);
    int e0 = Tscan[b], e1 = Tscan[b + 1];
    int m = e1 - e0;
    scnt[t] = 0; scur[t] = 0;
    __syncthreads();
    for (int i = t; i < m; i += 256)
        atomicAdd(&scnt[((unsigned)staged[e0 + i]) >> 24], 1);
    __syncthreads();
    int inc = scnt[t];
    for (int off = 1; off < 256; off <<= 1) {
        int add = (t >= off) ? scnt[t - off] : 0;
        __syncthreads();
        scnt[t] += add;
        __syncthreads();
    }
    int excl = scnt[t] - inc;
    srel[t] = excl;
    if (t < nn) rp[n0 + t] = e0 + excl;
    if (b == NBKT - 1 && t == 0) rp[N] = E;
    __syncthreads();
    if (m <= SCOL_CAP) {
        for (int i = t; i < m; i += 256) {
            int v = staged[e0 + i];
            int dl = ((unsigned)v) >> 24;
            int pos = srel[dl] + atomicAdd(&scur[dl], 1);
            scol[pos] = v & 0xFFFFFF;
        }
        __syncthreads();
        for (int i = t; i < m; i += 256) col[e0 + i] = scol[i];
    } else {
        for (int i = t; i < m; i += 256) {
            int v = staged[e0 + i];
            int dl = ((unsigned)v) >> 24;
            int pos = srel[dl] + atomicAdd(&scur[dl], 1);
            col[e0 + pos] = v & 0xFFFFFF;
        }
    }
}

template <bool RELU_OUT, bool OUT_BF16>
__global__ void agg_mlp_c(const ushort_t* __restrict__ xin, const int* __restrict__ rp,
                          const int* __restrict__ col,
                          const float* __restrict__ Wa, const float* __restrict__ ba,
                          const float* __restrict__ Wb, const float* __restrict__ bb,
                          void* __restrict__ outv, int N, int nchunks) {
    __shared__ AggSm A;
    int t = threadIdx.x;
    A.sWa[t] = Wa[t];  A.sWa[t + 256] = Wa[t + 256];
    A.sWb[t] = Wb[t];  A.sWb[t + 256] = Wb[t + 256];
    if (t < 16) A.sba[t] = ba[t];
    if (t < 32) A.sbb[t] = bb[t];
    const uint2* x2 = (const uint2*)xin;
    int c = blockIdx.x;
    if (c < nchunks)
        agg_chunk<RELU_OUT, OUT_BF16>(A, x2, rp, col, outv, N, c * NPB);
}

// ======================= launch ==========================================

extern "C" void kernel_launch(void* const* d_in, const int* in_sizes, int n_in,
                              void* d_out, int out_size, void* d_ws, size_t ws_size,
                              hipStream_t stream) {
    const float* x  = (const float*)d_in[0];
    const int*   ei = (const int*)d_in[1];

    const int N = in_sizes[0] / 32;
    const int E = in_sizes[1] / 2;
    const int NBKT = (N + BKT_NODES - 1) >> BKT_SHIFT;   // 782

    char* ws = (char*)d_ws;
    size_t o = 0;
    auto alloc = [&](size_t bytes) -> char* {
        o = (o + 255) & ~(size_t)255;
        char* r = ws + o;
        o += bytes;
        return r;
    };

    MegaP p;
    p.x   = (const float4*)x;
    p.src = ei;
    p.dst = ei + E;
    p.W1 = (const float*)d_in[2];  p.b1 = (const float*)d_in[3];
    p.W2 = (const float*)d_in[4];  p.b2 = (const float*)d_in[5];
    p.W3 = (const float*)d_in[6];  p.b3 = (const float*)d_in[7];
    p.W4 = (const float*)d_in[8];  p.b4 = (const float*)d_in[9];
    p.out = (float*)d_out;

    p.hist   = (int*)     alloc(4 * (size_t)MAXGRID * NBKT);
    p.T      = (int*)     alloc(4 * (size_t)NBKT);
    p.Tscan  = (int*)     alloc(4 * (size_t)(NBKT + 1));
    p.staged = (int*)     alloc(4 * (size_t)E);
    p.rp     = (int*)     alloc(4 * (size_t)(N + 1));
    p.col    = (int*)     alloc(4 * (size_t)E);
    p.xb     = (ushort_t*)alloc(2 * (size_t)N * 32);
    p.hb     = (ushort_t*)alloc(2 * (size_t)N * 32);

    p.N = N; p.E = E; p.NBKT = NBKT;
    p.n4 = N * 8;
    p.nchunks = (N + NPB - 1) / NPB;

    // co-residency-safe cooperative grid (host-side query; capture-safe)
    int maxB = 0;
    hipError_t qerr = hipOccupancyMaxActiveBlocksPerMultiprocessor(&maxB, mega, 256, 0);
    int grid = (qerr == hipSuccess) ? maxB * 256 : 0;   // 256 CUs on MI355X
    if (grid > MAXGRID) grid = MAXGRID;

    bool coop_ok = false;
    if (grid >= NBKT) {
        p.EPB2 = (E + grid - 1) / grid;
        void* kargs[] = { (void*)&p };
        hipError_t lerr = hipLaunchCooperativeKernel((const void*)mega, dim3(grid),
                                                     dim3(256), kargs, 0, stream);
        coop_ok = (lerr == hipSuccess);
        if (!coop_ok) (void)hipGetLastError();   // clear sticky error
    }

    if (!coop_ok) {
        // classic 7-kernel fallback (proven R11-style pipeline)
        const int NBLK = (E + EPB_C - 1) / EPB_C;
        to_bf16_c<<<(p.n4 + 255) / 256, 256, 0, stream>>>(p.x, p.xb, p.n4);
        histA_c<<<NBLK, 512, 0, stream>>>(p.dst, p.hist, E, NBKT);
        colscan_c<<<NBKT, 256, 0, stream>>>(p.hist, p.T, NBLK, NBKT);
        scan_small_c<<<1, 1024, 0, stream>>>(p.T, p.Tscan, NBKT, E);
        scatter_c<<<NBLK, 512, 0, stream>>>(p.src, p.dst, p.hist, p.Tscan,
                                            p.staged, E, NBKT);
        fine_fill_c<<<NBKT, 256, 0, stream>>>(p.staged, p.Tscan, p.rp, p.col,
                                              N, E, NBKT);
        agg_mlp_c<true,  true ><<<p.nchunks, 256, 0, stream>>>(p.xb, p.rp, p.col,
            p.W1, p.b1, p.W2, p.b2, p.hb, N, p.nchunks);
        agg_mlp_c<false, false><<<p.nchunks, 256, 0, stream>>>(p.hb, p.rp, p.col,
            p.W3, p.b3, p.W4, p.b4, d_out, N, p.nchunks);
    }
}

// Round 15
// 260.085 us; speedup vs baseline: 3.7754x; 3.7754x over previous
//
#include <hip/hip_runtime.h>

typedef unsigned short ushort_t;
typedef unsigned int uint_t;

#define BKT_SHIFT 8            // 256 dst-nodes per bucket
#define BKT_NODES 256
#define NBKT_MAX 400           // >= ceil(100000/256)=391
#define EPB 8192               // edges per block in hist/scatter (512 thr x 16)
#define SCOL_CAP 8192          // LDS col staging in fine_fill (32 KB); mean bucket = 6400
#define NPB 32                 // nodes per block in agg_mlp
#define SCOL_N 1536            // LDS col cache per agg block (mean 800, +26 sigma)

__device__ __forceinline__ ushort_t f2bf(float f) {
    unsigned u = __float_as_uint(f);
    unsigned r = (u + 0x7FFFu + ((u >> 16) & 1u)) >> 16;   // RNE
    return (ushort_t)r;
}
__device__ __forceinline__ float bflo(uint_t u) { return __uint_as_float(u << 16); }
__device__ __forceinline__ float bfhi(uint_t u) { return __uint_as_float(u & 0xFFFF0000u); }

// ---- ranked bucket sort (no global atomics on edge data) ----------------

// histA: fused x->bf16 convert (grid-stride) + per-block bucket histogram.
// Also zeroes the tail-block ticket for colscan (kernel-boundary ordering).
__global__ void histA(const float4* __restrict__ xin, ushort_t* __restrict__ xb, int n4,
                      const int* __restrict__ dst, int* __restrict__ hist,
                      int* __restrict__ done, int E, int NBKT) {
    __shared__ int lcnt[NBKT_MAX];
    int t = threadIdx.x, blk = blockIdx.x;
    if (blk == 0 && t == 0) *done = 0;
    int gid = blk * 512 + t;
    int gstr = gridDim.x * 512;
    for (int i = gid; i < n4; i += gstr) {
        float4 v = xin[i];
        xb[i * 4 + 0] = f2bf(v.x);
        xb[i * 4 + 1] = f2bf(v.y);
        xb[i * 4 + 2] = f2bf(v.z);
        xb[i * 4 + 3] = f2bf(v.w);
    }
    for (int b = t; b < NBKT; b += 512) lcnt[b] = 0;
    __syncthreads();
    int e0 = blk * EPB;
    #pragma unroll
    for (int i = 0; i < 16; ++i) {
        int e = e0 + i * 512 + t;
        if (e < E) atomicAdd(&lcnt[dst[e] >> BKT_SHIFT], 1);
    }
    __syncthreads();
    for (int b = t; b < NBKT; b += 512) hist[blk * NBKT + b] = lcnt[b];
}

// colscan + tail-block Tscan: block b scans hist column b (NBLK rows) in
// place, writes T[b]; the LAST block to finish also scans T -> Tscan.
__global__ void colscan(int* __restrict__ hist, int* __restrict__ T,
                        int* __restrict__ Tscan, int* __restrict__ done,
                        int NBLK, int NBKT, int E) {
    __shared__ int lds[256];
    __shared__ int is_last;
    int b = blockIdx.x, t = threadIdx.x;
    int j0 = t * 4;
    int v0 = (j0 + 0 < NBLK) ? hist[(j0 + 0) * NBKT + b] : 0;
    int v1 = (j0 + 1 < NBLK) ? hist[(j0 + 1) * NBKT + b] : 0;
    int v2 = (j0 + 2 < NBLK) ? hist[(j0 + 2) * NBKT + b] : 0;
    int v3 = (j0 + 3 < NBLK) ? hist[(j0 + 3) * NBKT + b] : 0;
    lds[t] = v0 + v1 + v2 + v3;
    __syncthreads();
    for (int off = 1; off < 256; off <<= 1) {
        int add = (t >= off) ? lds[t - off] : 0;
        __syncthreads();
        lds[t] += add;
        __syncthreads();
    }
    int p = (t == 0) ? 0 : lds[t - 1];
    if (j0 + 0 < NBLK) hist[(j0 + 0) * NBKT + b] = p;  p += v0;
    if (j0 + 1 < NBLK) hist[(j0 + 1) * NBKT + b] = p;  p += v1;
    if (j0 + 2 < NBLK) hist[(j0 + 2) * NBKT + b] = p;  p += v2;
    if (j0 + 3 < NBLK) hist[(j0 + 3) * NBKT + b] = p;
    if (t == 255) T[b] = lds[255];

    // tail-block election
    __threadfence();                        // make T[b] device-visible
    if (t == 0) {
        int ticket = atomicAdd(done, 1);
        is_last = (ticket == gridDim.x - 1) ? 1 : 0;
    }
    __syncthreads();
    if (is_last) {
        __threadfence();                    // acquire: see all T[b]
        int base = t * 4;
        int w0 = (base + 0 < NBKT) ? T[base + 0] : 0;
        int w1 = (base + 1 < NBKT) ? T[base + 1] : 0;
        int w2 = (base + 2 < NBKT) ? T[base + 2] : 0;
        int w3 = (base + 3 < NBKT) ? T[base + 3] : 0;
        __syncthreads();                    // reuse lds safely
        lds[t] = w0 + w1 + w2 + w3;
        __syncthreads();
        for (int off = 1; off < 256; off <<= 1) {
            int add = (t >= off) ? lds[t - off] : 0;
            __syncthreads();
            lds[t] += add;
            __syncthreads();
        }
        int pp = (t == 0) ? 0 : lds[t - 1];
        if (base + 0 < NBKT) Tscan[base + 0] = pp;  pp += w0;
        if (base + 1 < NBKT) Tscan[base + 1] = pp;  pp += w1;
        if (base + 2 < NBKT) Tscan[base + 2] = pp;  pp += w2;
        if (base + 3 < NBKT) Tscan[base + 3] = pp;
        if (t == 0) Tscan[NBKT] = E;
    }
}

__global__ void scatter_kernel(const int* __restrict__ src, const int* __restrict__ dst,
                               const int* __restrict__ hist, const int* __restrict__ Tscan,
                               int* __restrict__ staged, int E, int NBKT) {
    __shared__ int lbase[NBKT_MAX];
    __shared__ int lcur[NBKT_MAX];
    int t = threadIdx.x, blk = blockIdx.x;
    for (int b = t; b < NBKT; b += 512) {
        lbase[b] = hist[blk * NBKT + b] + Tscan[b];
        lcur[b] = 0;
    }
    __syncthreads();
    int e0 = blk * EPB;
    #pragma unroll
    for (int i = 0; i < 16; ++i) {
        int e = e0 + i * 512 + t;
        if (e < E) {
            int d = dst[e], s = src[e];
            int b = d >> BKT_SHIFT;
            int r = atomicAdd(&lcur[b], 1);
            staged[lbase[b] + r] = ((d & (BKT_NODES - 1)) << 24) | s;
        }
    }
}

// One block per bucket: per-(node, src-quartile) LDS count -> 1024-wide scan
// (writes rp!) -> LDS place -> coalesced col flush. Quartile sub-sort keeps
// the agg gather sweep phase-local in src space.
__global__ void fine_fill(const int* __restrict__ staged, const int* __restrict__ Tscan,
                          int* __restrict__ rp, int* __restrict__ col,
                          int N, int E, int NBKT, int q1, int q2, int q3) {
    __shared__ int scnt[1024];   // [node][quartile]
    __shared__ int srel[1024];
    __shared__ int scur[1024];
    __shared__ int swsum[256];
    __shared__ int scol[SCOL_CAP];
    int b = blockIdx.x, t = threadIdx.x;
    int n0 = b << BKT_SHIFT;
    int nn = min(BKT_NODES, N - n0);
    int e0 = Tscan[b];
    int e1 = Tscan[b + 1];
    int m = e1 - e0;

    #pragma unroll
    for (int j = 0; j < 4; ++j) { scnt[t * 4 + j] = 0; scur[t * 4 + j] = 0; }
    __syncthreads();
    for (int i = t; i < m; i += 256) {
        int v = staged[e0 + i];
        int dl = ((unsigned)v) >> 24;
        int s = v & 0xFFFFFF;
        int q = (s >= q2) ? ((s >= q3) ? 3 : 2) : ((s >= q1) ? 1 : 0);
        atomicAdd(&scnt[dl * 4 + q], 1);
    }
    __syncthreads();
    int c0 = scnt[t * 4 + 0], c1 = scnt[t * 4 + 1];
    int c2 = scnt[t * 4 + 2], c3 = scnt[t * 4 + 3];
    int tot = c0 + c1 + c2 + c3;
    swsum[t] = tot;
    __syncthreads();
    for (int off = 1; off < 256; off <<= 1) {   // Hillis-Steele inclusive over nodes
        int add = (t >= off) ? swsum[t - off] : 0;
        __syncthreads();
        swsum[t] += add;
        __syncthreads();
    }
    int excl = swsum[t] - tot;                  // node-exclusive prefix
    srel[t * 4 + 0] = excl;
    srel[t * 4 + 1] = excl + c0;
    srel[t * 4 + 2] = excl + c0 + c1;
    srel[t * 4 + 3] = excl + c0 + c1 + c2;
    if (t < nn) rp[n0 + t] = e0 + excl;
    if (b == NBKT - 1 && t == 0) rp[N] = E;
    __syncthreads();

    if (m <= SCOL_CAP) {
        for (int i = t; i < m; i += 256) {
            int v = staged[e0 + i];
            int dl = ((unsigned)v) >> 24;
            int s = v & 0xFFFFFF;
            int q = (s >= q2) ? ((s >= q3) ? 3 : 2) : ((s >= q1) ? 1 : 0);
            int p = srel[dl * 4 + q] + atomicAdd(&scur[dl * 4 + q], 1);
            scol[p] = s;
        }
        __syncthreads();
        for (int i = t; i < m; i += 256) col[e0 + i] = scol[i];
    } else {  // statistically unreachable overflow fallback
        for (int i = t; i < m; i += 256) {
            int v = staged[e0 + i];
            int dl = ((unsigned)v) >> 24;
            int s = v & 0xFFFFFF;
            int q = (s >= q2) ? ((s >= q3) ? 3 : 2) : ((s >= q1) ? 1 : 0);
            int p = srel[dl * 4 + q] + atomicAdd(&scur[dl * 4 + q], 1);
            col[e0 + p] = s;
        }
    }
}

// ---- Fused aggregate + MLP (R11's proven structure) ---------------------
// Block = 256 threads = 32 nodes x 8 lanes; each lane handles 4 channels via
// uint2 (8B) loads => one gather instruction serves 8 edges (8 nodes/wave).
// col prefetched to LDS nontemporal; sv/st1 padded (33/17) for bank-freedom.

template <bool RELU_OUT, bool OUT_BF16>
__global__ void agg_mlp(const ushort_t* __restrict__ xin, const int* __restrict__ rp,
                        const int* __restrict__ col,
                        const float* __restrict__ Wa, const float* __restrict__ ba,
                        const float* __restrict__ Wb, const float* __restrict__ bb,
                        void* __restrict__ outv, int N) {
    __shared__ float sWa[32 * 16];
    __shared__ float sWb[16 * 32];
    __shared__ float sba[16], sbb[32];
    __shared__ float sv[NPB * 33];
    __shared__ float st1[NPB * 17];
    __shared__ int scol[SCOL_N];

    int t = threadIdx.x;
    sWa[t] = Wa[t];  sWa[t + 256] = Wa[t + 256];
    sWb[t] = Wb[t];  sWb[t + 256] = Wb[t + 256];
    if (t < 16) sba[t] = ba[t];
    if (t < 32) sbb[t] = bb[t];

    int base = blockIdx.x * NPB;
    int kb = rp[base];
    int kt = rp[min(base + NPB, N)];
    int tot = kt - kb;
    bool ovf = (tot > SCOL_N);
    if (!ovf) {
        for (int i = t; i < tot; i += 256)
            scol[i] = __builtin_nontemporal_load(col + kb + i);
    }
    __syncthreads();

    int ln = t >> 3;          // node slot 0..31
    int sl = t & 7;           // channels 4*sl .. 4*sl+3
    int n  = base + ln;
    bool act = (n < N);
    const uint2* x2 = (const uint2*)xin;   // row = 8 uint2 (32 bf16)

    if (act) {
        uint2 us = x2[(size_t)n * 8 + sl];
        float v0 = bflo(us.x), v1 = bfhi(us.x), v2 = bflo(us.y), v3 = bfhi(us.y);
        int ks = rp[n], ke = rp[n + 1];
        if (!ovf) {
            int k = ks - kb, kend = ke - kb;
            for (; k + 8 <= kend; k += 8) {
                int s0 = scol[k + 0], s1 = scol[k + 1], s2 = scol[k + 2], s3 = scol[k + 3];
                int s4 = scol[k + 4], s5 = scol[k + 5], s6 = scol[k + 6], s7 = scol[k + 7];
                uint2 u0 = x2[(size_t)s0 * 8 + sl];
                uint2 u1 = x2[(size_t)s1 * 8 + sl];
                uint2 u2 = x2[(size_t)s2 * 8 + sl];
                uint2 u3 = x2[(size_t)s3 * 8 + sl];
                uint2 u4 = x2[(size_t)s4 * 8 + sl];
                uint2 u5 = x2[(size_t)s5 * 8 + sl];
                uint2 u6 = x2[(size_t)s6 * 8 + sl];
                uint2 u7 = x2[(size_t)s7 * 8 + sl];
                v0 += ((bflo(u0.x) + bflo(u1.x)) + (bflo(u2.x) + bflo(u3.x)))
                    + ((bflo(u4.x) + bflo(u5.x)) + (bflo(u6.x) + bflo(u7.x)));
                v1 += ((bfhi(u0.x) + bfhi(u1.x)) + (bfhi(u2.x) + bfhi(u3.x)))
                    + ((bfhi(u4.x) + bfhi(u5.x)) + (bfhi(u6.x) + bfhi(u7.x)));
                v2 += ((bflo(u0.y) + bflo(u1.y)) + (bflo(u2.y) + bflo(u3.y)))
                    + ((bflo(u4.y) + bflo(u5.y)) + (bflo(u6.y) + bflo(u7.y)));
                v3 += ((bfhi(u0.y) + bfhi(u1.y)) + (bfhi(u2.y) + bfhi(u3.y)))
                    + ((bfhi(u4.y) + bfhi(u5.y)) + (bfhi(u6.y) + bfhi(u7.y)));
            }
            for (; k < kend; ++k) {
                uint2 u = x2[(size_t)scol[k] * 8 + sl];
                v0 += bflo(u.x); v1 += bfhi(u.x); v2 += bflo(u.y); v3 += bfhi(u.y);
            }
        } else {  // statistically unreachable
            for (int k = ks; k < ke; ++k) {
                uint2 u = x2[(size_t)col[k] * 8 + sl];
                v0 += bflo(u.x); v1 += bfhi(u.x); v2 += bflo(u.y); v3 += bfhi(u.y);
            }
        }
        int c0 = sl * 4;
        sv[ln * 33 + c0 + 0] = v0; sv[ln * 33 + c0 + 1] = v1;
        sv[ln * 33 + c0 + 2] = v2; sv[ln * 33 + c0 + 3] = v3;
    }
    __syncthreads();

    if (act) {   // hidden units sl and sl+8 for node ln
        float ha = sba[sl], hb = sba[sl + 8];
        #pragma unroll
        for (int cc = 0; cc < 32; ++cc) {
            float vc = sv[ln * 33 + cc];
            ha += vc * sWa[cc * 16 + sl];
            hb += vc * sWa[cc * 16 + sl + 8];
        }
        st1[ln * 17 + sl]     = fmaxf(ha, 0.f);
        st1[ln * 17 + sl + 8] = fmaxf(hb, 0.f);
    }
    __syncthreads();

    if (act) {   // out channels 4*sl .. 4*sl+3 for node ln
        int c0 = sl * 4;
        float a0 = sbb[c0], a1 = sbb[c0 + 1], a2 = sbb[c0 + 2], a3 = sbb[c0 + 3];
        #pragma unroll
        for (int j = 0; j < 16; ++j) {
            float hj = st1[ln * 17 + j];
            a0 += hj * sWb[j * 32 + c0];
            a1 += hj * sWb[j * 32 + c0 + 1];
            a2 += hj * sWb[j * 32 + c0 + 2];
            a3 += hj * sWb[j * 32 + c0 + 3];
        }
        if (RELU_OUT) {
            a0 = fmaxf(a0, 0.f); a1 = fmaxf(a1, 0.f);
            a2 = fmaxf(a2, 0.f); a3 = fmaxf(a3, 0.f);
        }
        if (OUT_BF16) {
            uint_t p0 = (uint_t)f2bf(a0) | ((uint_t)f2bf(a1) << 16);
            uint_t p1 = (uint_t)f2bf(a2) | ((uint_t)f2bf(a3) << 16);
            uint_t* o = (uint_t*)outv + (size_t)n * 16 + sl * 2;
            __builtin_nontemporal_store(p0, o);
            __builtin_nontemporal_store(p1, o + 1);
        } else {
            float* o = (float*)outv + (size_t)n * 32 + c0;
            __builtin_nontemporal_store(a0, o);
            __builtin_nontemporal_store(a1, o + 1);
            __builtin_nontemporal_store(a2, o + 2);
            __builtin_nontemporal_store(a3, o + 3);
        }
    }
}

// ---- Launch -------------------------------------------------------------

extern "C" void kernel_launch(void* const* d_in, const int* in_sizes, int n_in,
                              void* d_out, int out_size, void* d_ws, size_t ws_size,
                              hipStream_t stream) {
    const float* x  = (const float*)d_in[0];
    const int*   ei = (const int*)d_in[1];
    const float* W1 = (const float*)d_in[2];
    const float* b1 = (const float*)d_in[3];
    const float* W2 = (const float*)d_in[4];
    const float* b2 = (const float*)d_in[5];
    const float* W3 = (const float*)d_in[6];
    const float* b3 = (const float*)d_in[7];
    const float* W4 = (const float*)d_in[8];
    const float* b4 = (const float*)d_in[9];

    const int N = in_sizes[0] / 32;
    const int E = in_sizes[1] / 2;
    const int* src = ei;
    const int* dst = ei + E;

    const int NBKT = (N + BKT_NODES - 1) >> BKT_SHIFT;   // 391
    const int NBLK = (E + EPB - 1) / EPB;                // 306

    char* ws = (char*)d_ws;
    size_t o = 0;
    auto alloc = [&](size_t bytes) -> char* {
        o = (o + 255) & ~(size_t)255;
        char* r = ws + o;
        o += bytes;
        return r;
    };
    int*      hist   = (int*)     alloc(4 * (size_t)NBLK * NBKT);
    int*      T      = (int*)     alloc(4 * (size_t)NBKT);
    int*      Tscan  = (int*)     alloc(4 * (size_t)(NBKT + 1));
    int*      done   = (int*)     alloc(4);
    int*      staged = (int*)     alloc(4 * (size_t)E);
    int*      rp     = (int*)     alloc(4 * (size_t)(N + 1));
    int*      col    = (int*)     alloc(4 * (size_t)E);
    ushort_t* xb     = (ushort_t*)alloc(2 * (size_t)N * 32);
    ushort_t* hb     = (ushort_t*)alloc(2 * (size_t)N * 32);

    int n4 = N * 8;
    histA<<<NBLK, 512, 0, stream>>>((const float4*)x, xb, n4, dst, hist, done, E, NBKT);
    colscan<<<NBKT, 256, 0, stream>>>(hist, T, Tscan, done, NBLK, NBKT, E);
    scatter_kernel<<<NBLK, 512, 0, stream>>>(src, dst, hist, Tscan, staged, E, NBKT);
    int q1 = N / 4, q2 = N / 2, q3 = (3 * N) / 4;
    fine_fill<<<NBKT, 256, 0, stream>>>(staged, Tscan, rp, col, N, E, NBKT, q1, q2, q3);

    agg_mlp<true,  true ><<<(N + NPB - 1) / NPB, 256, 0, stream>>>(xb, rp, col,
                                                                   W1, b1, W2, b2, hb, N);
    agg_mlp<false, false><<<(N + NPB - 1) / NPB, 256, 0, stream>>>(hb, rp, col,
                                                                   W3, b3, W4, b4, d_out, N);
}